// Round 1
// baseline (5380.803 us; speedup 1.0000x reference)
//
#include <hip/hip_runtime.h>

#define DIMN 10
#define PASTLEN 3
#define HID 128
#define TSTEPS 512
#define BATCH 2048
#define XLEN 30        // PASTLEN*DIMN
#define NOUT 110       // 10 drift + 100 diff
#define ZCHUNK 128     // timesteps of z staged in LDS at a time

__global__ __launch_bounds__(512, 2)
void sde_kernel(const float* __restrict__ init_state,
                const float* __restrict__ z,
                const float* __restrict__ dr_w1, const float* __restrict__ dr_b1,
                const float* __restrict__ dr_w2, const float* __restrict__ dr_b2,
                const float* __restrict__ dr_w3, const float* __restrict__ dr_b3,
                const float* __restrict__ df_w1, const float* __restrict__ df_b1,
                const float* __restrict__ df_w2, const float* __restrict__ df_b2,
                const float* __restrict__ df_w3, const float* __restrict__ df_b3,
                float* __restrict__ out)
{
    const int tid = threadIdx.x;
    const int b   = blockIdx.x;

    __shared__ float xbuf[2][32];          // ping-pong state window (30 used)
    __shared__ float h1buf[256];           // [0:128) drift, [128:256) diff
    __shared__ float h2buf[256];
    __shared__ float outv[NOUT];           // [0:10) drift, [10:110) diff flat
    __shared__ float zch[ZCHUNK * DIMN];

    // ---- roles for h-layers: neuron n = tid>>1, k-half = tid&1 ----
    const int n   = tid >> 1;              // 0..255
    const int kh  = tid & 1;
    const int col = n & 127;
    const int mlp = n >> 7;                // 0 = drift, 1 = diff
    const float* w1p = mlp ? df_w1 : dr_w1;
    const float* w2p = mlp ? df_w2 : dr_w2;

    float w1h[15];
#pragma unroll
    for (int j = 0; j < 15; ++j) w1h[j] = w1p[(kh * 15 + j) * HID + col];
    const float b1v = (mlp ? df_b1 : dr_b1)[col];

    float w2h[64];
#pragma unroll
    for (int j = 0; j < 64; ++j) w2h[j] = w2p[(kh * 64 + j) * HID + col];
    const float b2v = (mlp ? df_b2 : dr_b2)[col];

    // ---- roles for output layer: o = tid>>2 (110 outputs), k-quarter = tid&3 ----
    const int o  = tid >> 2;
    const int kq = tid & 3;
    const bool has_out = (tid < 4 * NOUT);
    const bool odrift  = (o < DIMN);
    float w3q[32];
    float b3v = 0.f;
    int obase = 0;
    if (has_out) {
        const float* w3p = odrift ? dr_w3 : df_w3;
        const int ocol   = odrift ? o : (o - DIMN);
        const int onc    = odrift ? DIMN : (DIMN * DIMN);
        obase            = odrift ? 0 : 128;
#pragma unroll
        for (int j = 0; j < 32; ++j) w3q[j] = w3p[(kq * 32 + j) * onc + ocol];
        b3v = (odrift ? dr_b3 : df_b3)[ocol];
    }

    // ---- init state window: x = [s_{-3}(0:10), s_{-2}(10:20), s_{-1}(20:30)] ----
    if (tid < XLEN) {
        const int p = tid / DIMN, d = tid % DIMN;
        xbuf[0][tid] = init_state[(p * BATCH + b) * DIMN + d];
    }
    __syncthreads();

    int cur = 0;
    for (int t = 0; t < TSTEPS; ++t) {
        if ((t & (ZCHUNK - 1)) == 0) {
            for (int idx = tid; idx < ZCHUNK * DIMN; idx += 512) {
                const int tl = idx / DIMN, d = idx % DIMN;
                zch[idx] = z[((size_t)(t + tl) * BATCH + b) * DIMN + d];
            }
            __syncthreads();
        }
        const float* xc = xbuf[cur];

        // ---- h1 = relu(x @ W1 + b1) ----
        float acc = 0.f;
#pragma unroll
        for (int j = 0; j < 15; ++j) acc += xc[kh * 15 + j] * w1h[j];
        acc += __shfl_xor(acc, 1);
        if (kh == 0) h1buf[n] = fmaxf(b1v + acc, 0.f);
        __syncthreads();

        // ---- h2 = relu(h1 @ W2 + b2) ----
        acc = 0.f;
        {
            const float* h1s = &h1buf[mlp * 128 + kh * 64];
#pragma unroll
            for (int j = 0; j < 64; ++j) acc += h1s[j] * w2h[j];
        }
        acc += __shfl_xor(acc, 1);
        if (kh == 0) h2buf[n] = fmaxf(b2v + acc, 0.f);
        __syncthreads();

        // ---- out = h2 @ W3 + b3  (110 outputs: 10 drift + 100 diff) ----
        if (has_out) {
            acc = 0.f;
            const float* h2s = &h2buf[obase + kq * 32];
#pragma unroll
            for (int j = 0; j < 32; ++j) acc += h2s[j] * w3q[j];
            acc += __shfl_xor(acc, 1);
            acc += __shfl_xor(acc, 2);
            if (kq == 0) outv[o] = b3v + acc;
        }
        __syncthreads();

        // ---- nxt = last + drift + diff @ z_t ; shift window (into other buffer) ----
        float* xn = xbuf[cur ^ 1];
        if (tid < 20) xn[tid] = xc[tid + DIMN];          // new[0:20) = old[10:30)
        if (tid < DIMN) {
            const float* zt = &zch[(t & (ZCHUNK - 1)) * DIMN];
            float v = xc[20 + tid] + outv[tid];
#pragma unroll
            for (int j = 0; j < DIMN; ++j) v += outv[DIMN + tid * DIMN + j] * zt[j];
            xn[20 + tid] = v;
            out[((size_t)t * BATCH + b) * DIMN + tid] = v;
        }
        cur ^= 1;
        __syncthreads();
    }
}

extern "C" void kernel_launch(void* const* d_in, const int* in_sizes, int n_in,
                              void* d_out, int out_size, void* d_ws, size_t ws_size,
                              hipStream_t stream) {
    const float* init_state = (const float*)d_in[0];
    const float* z          = (const float*)d_in[1];
    const float* dr_w1 = (const float*)d_in[2];
    const float* dr_b1 = (const float*)d_in[3];
    const float* dr_w2 = (const float*)d_in[4];
    const float* dr_b2 = (const float*)d_in[5];
    const float* dr_w3 = (const float*)d_in[6];
    const float* dr_b3 = (const float*)d_in[7];
    const float* df_w1 = (const float*)d_in[8];
    const float* df_b1 = (const float*)d_in[9];
    const float* df_w2 = (const float*)d_in[10];
    const float* df_b2 = (const float*)d_in[11];
    const float* df_w3 = (const float*)d_in[12];
    const float* df_b3 = (const float*)d_in[13];
    float* outp = (float*)d_out;

    sde_kernel<<<BATCH, 512, 0, stream>>>(init_state, z,
                                          dr_w1, dr_b1, dr_w2, dr_b2, dr_w3, dr_b3,
                                          df_w1, df_b1, df_w2, df_b2, df_w3, df_b3,
                                          outp);
}